// Round 5
// baseline (69.888 us; speedup 1.0000x reference)
//
#include <hip/hip_runtime.h>
#include <hip/hip_bf16.h>

#define N2 16384
#define D  128
#define PANEL 32768                       // bytes per 128x128 bf16 panel
#define HALFP 16384                       // bytes per 64x128 half panel
#define SQC1 1.69864360258810896f         // sqrt(2*log2(e)), folded into zn
#define LN2  0.69314718055994530942f

typedef __bf16 bf16x8 __attribute__((ext_vector_type(8)));
typedef float  f32x4  __attribute__((ext_vector_type(4)));

#if __has_builtin(__builtin_amdgcn_exp2f)
#define EXP2(x) __builtin_amdgcn_exp2f(x)
#else
#define EXP2(x) exp2f(x)
#endif

__device__ __forceinline__ unsigned short f2bf(float f) {
    union { float f; unsigned u; } v; v.f = f;
    unsigned r = v.u + 0x7fffu + ((v.u >> 16) & 1u);
    return (unsigned short)(r >> 16);
}

// stage a full 128-row panel (32KB): 8 x global_load_lds(16B) per wave.
// LDS dest linear; XOR swizzle on the GLOBAL source (involution); reads
// use byte ^ ((row&7)<<4). (rule #21)
__device__ __forceinline__ void stage_panel(const char* __restrict__ g,
                                            char* lds, int tid) {
    const int wid = tid >> 6, lane = tid & 63;
    #pragma unroll
    for (int i = 0; i < 8; ++i) {
        int off = (wid << 13) + (i << 10) + (lane << 4);
        int src = off ^ (((off >> 8) & 7) << 4);
        __builtin_amdgcn_global_load_lds(
            (const __attribute__((address_space(1))) unsigned*)(g + src),
            (__attribute__((address_space(3))) unsigned*)(lds + (wid << 13) + (i << 10)),
            16, 0, 0);
    }
}

// stage a 64-row half panel (16KB): 4 x global_load_lds(16B) per wave
__device__ __forceinline__ void stage_half(const char* __restrict__ g,
                                           char* lds, int tid) {
    const int wid = tid >> 6, lane = tid & 63;
    #pragma unroll
    for (int i = 0; i < 4; ++i) {
        int off = (wid << 12) + (i << 10) + (lane << 4);
        int src = off ^ (((off >> 8) & 7) << 4);
        __builtin_amdgcn_global_load_lds(
            (const __attribute__((address_space(1))) unsigned*)(g + src),
            (__attribute__((address_space(3))) unsigned*)(lds + (wid << 12) + (i << 10)),
            16, 0, 0);
    }
}

// ---------- kernel 1: row L2-normalize -> bf16 sqrt(C1)*zn, + zero rowsum/out ----------
__global__ void k_norm(const float* __restrict__ z, unsigned short* __restrict__ zn,
                       float* __restrict__ rowsum, float* __restrict__ out) {
    if (blockIdx.x < 64) rowsum[blockIdx.x * 256 + threadIdx.x] = 0.f;
    if (blockIdx.x == 64 && threadIdx.x == 0) out[0] = 0.f;
    int row  = blockIdx.x * 4 + (threadIdx.x >> 6);
    int lane = threadIdx.x & 63;
    const float2 v = ((const float2*)(z + (size_t)row * D))[lane];
    float ss = v.x * v.x + v.y * v.y;
    #pragma unroll
    for (int m = 1; m < 64; m <<= 1) ss += __shfl_xor(ss, m);
    float inv = SQC1 / fmaxf(sqrtf(ss), 1e-12f);
    ushort2 o; o.x = f2bf(v.x * inv); o.y = f2bf(v.y * inv);
    ((ushort2*)(zn + (size_t)row * D))[lane] = o;
}

// ---------- kernel 2: symmetric fused sim GEMM + exp row/col sums ----------
// block (c, ti): s in [11c, min(11c+11,64)), c==5 adds s=64 when ti<64.
// Per tile jt=(ti+s)&127, processed as two 128x64 halves; A in regs; B half
// panels double-buffered in 2x16KB. Wave grid 2x2 over each half (64x32/wave).
__global__ __launch_bounds__(256, 3)
void k_sim(const unsigned short* __restrict__ zn, float* __restrict__ rowsum) {
    __shared__ char ls[PANEL];            // A stage, then 2x16KB B half dbuf
    char* ls0 = ls;                       // named pointers, NOT a pointer array
    char* ls1 = ls + HALFP;               // (array init hits the addrspacecast
                                          //  static-initializer bug on gfx950)
    const int tileI = blockIdx.y;
    const int c = blockIdx.x;
    const int sLo = c * 11;
    const int sHi = (c < 5) ? (sLo + 11) : ((tileI < 64) ? 65 : 64);
    const int Q = (sHi - sLo) * 2;        // half-steps

    const int tid  = threadIdx.x;
    const int lane = tid & 63, wid = tid >> 6;
    const int wr = wid >> 1, wc = wid & 1;          // 2x2 waves: 64 rows x 32 cols
    const int l16 = lane & 15, lg = lane >> 4;
    const char* znb = (const char*)zn;
    const f32x4 ZERO = {0.f, 0.f, 0.f, 0.f};

    // prologue: stage A(ti), extract A fragments to registers
    stage_panel(znb + (size_t)tileI * PANEL, ls0, tid);
    asm volatile("s_waitcnt vmcnt(0)" ::: "memory");
    __builtin_amdgcn_s_barrier();

    bf16x8 af[4][4];                                   // [kk][m], 64 rows/wave-row
    #pragma unroll
    for (int kk = 0; kk < 4; ++kk)
        #pragma unroll
        for (int m = 0; m < 4; ++m) {
            int row = wr * 64 + m * 16 + l16;
            int d = row * 256 + kk * 64 + lg * 16;
            af[kk][m] = *(const bf16x8*)(ls0 + (d ^ ((row & 7) << 4)));
        }
    asm volatile("s_waitcnt lgkmcnt(0)" ::: "memory");
    __builtin_amdgcn_s_barrier();                      // LDS now reusable for B

    // stage first B half (s=sLo, h=0)
    stage_half(znb + (size_t)((tileI + sLo) & 127) * PANEL, ls0, tid);

    float rs[4][4];
    #pragma unroll
    for (int m = 0; m < 4; ++m)
        #pragma unroll
        for (int r = 0; r < 4; ++r) rs[m][r] = 0.f;

    for (int q = 0; q < Q; ++q) {
        const int s  = sLo + (q >> 1);
        const int h  = q & 1;
        const int jt = (tileI + s) & 127;
        char* rbuf = (q & 1) ? ls1 : ls0;
        char* sbuf = (q & 1) ? ls0 : ls1;
        if (q + 1 < Q) {
            const int s1 = sLo + ((q + 1) >> 1);
            const int h1 = (q + 1) & 1;
            stage_half(znb + (size_t)((tileI + s1) & 127) * PANEL + h1 * HALFP,
                       sbuf, tid);
            asm volatile("s_waitcnt vmcnt(4)" ::: "memory");  // cur half landed
        } else {
            asm volatile("s_waitcnt vmcnt(0)" ::: "memory");
        }
        __builtin_amdgcn_s_barrier();

        bf16x8 bfr[4][2];                              // [kk][n], 32 cols/wave-col
        #pragma unroll
        for (int kk = 0; kk < 4; ++kk)
            #pragma unroll
            for (int n = 0; n < 2; ++n) {
                int row = wc * 32 + n * 16 + l16;      // local row in 64-row half
                int d = row * 256 + kk * 64 + lg * 16;
                bfr[kk][n] = *(const bf16x8*)(rbuf + (d ^ ((row & 7) << 4)));
            }
        asm volatile("s_waitcnt lgkmcnt(0)" ::: "memory");
        __builtin_amdgcn_s_barrier();                  // rbuf free for next stage

        f32x4 acc[4][2];
        #pragma unroll
        for (int m = 0; m < 4; ++m)
            #pragma unroll
            for (int n = 0; n < 2; ++n)
                acc[m][n] = __builtin_amdgcn_mfma_f32_16x16x32_bf16(af[0][m], bfr[0][n], ZERO, 0, 0, 0);
        #pragma unroll
        for (int kk = 1; kk < 4; ++kk)
            #pragma unroll
            for (int m = 0; m < 4; ++m)
                #pragma unroll
                for (int n = 0; n < 2; ++n)
                    acc[m][n] = __builtin_amdgcn_mfma_f32_16x16x32_bf16(af[kk][m], bfr[kk][n], acc[m][n], 0, 0, 0);

        // epilogue: e = exp2(acc) = exp(sim)
        if (s == 0) {
            // diagonal tile: mask self-sim, row sums only
            #pragma unroll
            for (int m = 0; m < 4; ++m)
                #pragma unroll
                for (int r = 0; r < 4; ++r) {
                    int li = wr * 64 + m * 16 + lg * 4 + r;
                    float a = 0.f;
                    #pragma unroll
                    for (int n = 0; n < 2; ++n) {
                        int lj = h * 64 + wc * 32 + n * 16 + l16;
                        float e = EXP2(acc[m][n][r]);
                        a += (li == lj) ? 0.f : e;
                    }
                    rs[m][r] += a;
                }
        } else {
            float cs0 = 0.f, cs1 = 0.f;
            #pragma unroll
            for (int m = 0; m < 4; ++m)
                #pragma unroll
                for (int r = 0; r < 4; ++r) {
                    float e0 = EXP2(acc[m][0][r]);
                    float e1 = EXP2(acc[m][1][r]);
                    rs[m][r] += e0 + e1;
                    cs0 += e0; cs1 += e1;
                }
            // column flush: reduce over the 4 lg row-groups of this wave
            float v0 = cs0 + __shfl_xor(cs0, 16);
            v0 += __shfl_xor(v0, 32);
            float v1 = cs1 + __shfl_xor(cs1, 16);
            v1 += __shfl_xor(v1, 32);
            if (lg == 0) {
                atomicAdd(&rowsum[jt * 128 + h * 64 + wc * 32 + l16], v0);
                atomicAdd(&rowsum[jt * 128 + h * 64 + wc * 32 + 16 + l16], v1);
            }
        }
    }

    // final: row sums -> reduce across 16 column-lanes, one atomic/row
    #pragma unroll
    for (int m = 0; m < 4; ++m)
        #pragma unroll
        for (int r = 0; r < 4; ++r) {
            float v = rs[m][r];
            v += __shfl_xor(v, 1);
            v += __shfl_xor(v, 2);
            v += __shfl_xor(v, 4);
            v += __shfl_xor(v, 8);
            if (l16 == 0)
                atomicAdd(&rowsum[tileI * 128 + wr * 64 + m * 16 + lg * 4 + r], v);
        }
}

// ---------- kernel 3: fused loss + mean ----------
// mean loss = (1/N2) * [ sum_i ln(rowsum_i) - ln2 * sum_{i,k} zn'[i][k]*zn'[i^1][k] ]
__global__ void k_loss_reduce(const unsigned short* __restrict__ zn,
                              const float* __restrict__ rowsum,
                              float* __restrict__ out) {
    const int tid = threadIdx.x + blockIdx.x * 256;   // 64 blocks x 256
    float p = 0.f;
    const bf16x8* v8 = (const bf16x8*)zn;
    for (int v = tid; v < N2 * D / 8; v += 64 * 256) {
        bf16x8 a = v8[v];
        bf16x8 b = v8[v ^ 16];                        // row i^1, same k-slice
        #pragma unroll
        for (int e = 0; e < 8; ++e) p += (float)a[e] * (float)b[e];
    }
    float part = logf(rowsum[tid]) - LN2 * p;         // exactly one row per thread

    __shared__ float sm[4];
    #pragma unroll
    for (int m = 1; m < 64; m <<= 1) part += __shfl_xor(part, m);
    if ((threadIdx.x & 63) == 0) sm[threadIdx.x >> 6] = part;
    __syncthreads();
    if (threadIdx.x == 0)
        atomicAdd(out, (sm[0] + sm[1] + sm[2] + sm[3]) * (1.0f / (float)N2));
}

extern "C" void kernel_launch(void* const* d_in, const int* in_sizes, int n_in,
                              void* d_out, int out_size, void* d_ws, size_t ws_size,
                              hipStream_t stream) {
    const float* z = (const float*)d_in[0];
    float* out = (float*)d_out;

    unsigned short* zn = (unsigned short*)d_ws;                       // 4 MiB
    float* rowsum = (float*)((char*)d_ws + (size_t)N2 * D * 2);       // 64 KiB

    k_norm<<<N2 / 4 , 256, 0, stream>>>(z, zn, rowsum, out);
    dim3 grid(6, 128);                                                // s-chunks x i-tiles
    k_sim<<<grid, 256, 0, stream>>>(zn, rowsum);
    k_loss_reduce<<<64, 256, 0, stream>>>(zn, rowsum, out);
}